// Round 1
// baseline (971.719 us; speedup 1.0000x reference)
//
#include <hip/hip_runtime.h>
#include <hip/hip_bf16.h>
#include <math.h>

#define NN 50000
#define NE 800000
#define ET (NE + NN)
#define DF 128
#define NH 4
#define HD 512
#define BN_EPS 1e-5f

typedef __hip_bfloat16 bf16;
typedef __hip_bfloat162 bf162;

// ---------- GEMM: Hout[M,512](bf16) = A[M,128](f32) @ W[128,512](f32) ----------
__global__ __launch_bounds__(256) void gemm_proj(const float* __restrict__ A,
                                                 const float* __restrict__ W,
                                                 bf16* __restrict__ Hout,
                                                 int M) {
    __shared__ float As[128][68];   // [k][row], transposed A tile (64 rows)
    __shared__ float Ws[128][36];   // [k][n]   (32 cols)
    const int tid = threadIdx.x;
    const int m0 = blockIdx.x * 64;
    const int n0 = blockIdx.y * 32;
    #pragma unroll
    for (int i = 0; i < 32; ++i) {
        int idx = tid + i * 256;          // 0..8191 over 64x128
        int r = idx >> 7, k = idx & 127;
        int gr = m0 + r;
        As[k][r] = (gr < M) ? A[gr * DF + k] : 0.f;
    }
    #pragma unroll
    for (int i = 0; i < 16; ++i) {
        int idx = tid + i * 256;          // 0..4095 over 128x32
        int k = idx >> 5, n = idx & 31;
        Ws[k][n] = W[k * HD + n0 + n];
    }
    __syncthreads();
    const int tx = tid & 15;              // 16 * 2 cols
    const int ty = tid >> 4;              // 16 * 4 rows
    float acc[4][2] = {};
    #pragma unroll 8
    for (int k = 0; k < 128; ++k) {
        float4 a = *reinterpret_cast<const float4*>(&As[k][ty * 4]);
        float2 b = *reinterpret_cast<const float2*>(&Ws[k][tx * 2]);
        acc[0][0] += a.x * b.x; acc[0][1] += a.x * b.y;
        acc[1][0] += a.y * b.x; acc[1][1] += a.y * b.y;
        acc[2][0] += a.z * b.x; acc[2][1] += a.z * b.y;
        acc[3][0] += a.w * b.x; acc[3][1] += a.w * b.y;
    }
    #pragma unroll
    for (int i = 0; i < 4; ++i) {
        int gr = m0 + ty * 4 + i;
        if (gr < M) {
            bf162 p;
            p.x = __float2bfloat16(acc[i][0]);
            p.y = __float2bfloat16(acc[i][1]);
            reinterpret_cast<bf162*>(Hout)[(gr * HD + n0 + tx * 2) >> 1] = p;
        }
    }
}

// ---------- per-node attention scores: a_src[n,h] = <h[n,h,:], as[h,:]> ----------
__global__ __launch_bounds__(64) void att_scores(const bf16* __restrict__ H,
                                                 const float* __restrict__ as,
                                                 const float* __restrict__ ad,
                                                 float* __restrict__ a_src,
                                                 float* __restrict__ a_dst) {
    const int n = blockIdx.x;
    const int l = threadIdx.x;
    float ps[NH], pd[NH];
    #pragma unroll
    for (int h = 0; h < NH; ++h) {
        float v0 = __bfloat162float(H[n * HD + h * DF + l]);
        float v1 = __bfloat162float(H[n * HD + h * DF + l + 64]);
        ps[h] = v0 * as[h * DF + l] + v1 * as[h * DF + l + 64];
        pd[h] = v0 * ad[h * DF + l] + v1 * ad[h * DF + l + 64];
    }
    #pragma unroll
    for (int off = 32; off > 0; off >>= 1) {
        #pragma unroll
        for (int h = 0; h < NH; ++h) {
            ps[h] += __shfl_down(ps[h], off);
            pd[h] += __shfl_down(pd[h], off);
        }
    }
    if (l == 0) {
        #pragma unroll
        for (int h = 0; h < NH; ++h) {
            a_src[n * NH + h] = ps[h];
            a_dst[n * NH + h] = pd[h];
        }
    }
}

// ---------- CSR build ----------
__global__ void count_deg(const int* __restrict__ ei, int* __restrict__ counts) {
    int e = blockIdx.x * blockDim.x + threadIdx.x;
    if (e >= ET) return;
    int d = (e < NE) ? ei[NE + e] : (e - NE);
    atomicAdd(&counts[d], 1);
}

__global__ __launch_bounds__(256) void scan1(const int* __restrict__ counts, int* __restrict__ bsum) {
    __shared__ int sd[256];
    int i = blockIdx.x * 256 + threadIdx.x;
    sd[threadIdx.x] = (i < NN) ? counts[i] : 0;
    __syncthreads();
    for (int s = 128; s > 0; s >>= 1) {
        if (threadIdx.x < s) sd[threadIdx.x] += sd[threadIdx.x + s];
        __syncthreads();
    }
    if (threadIdx.x == 0) bsum[blockIdx.x] = sd[0];
}

__global__ void scan2(int* __restrict__ bsum, int nb) {
    if (threadIdx.x == 0 && blockIdx.x == 0) {
        int acc = 0;
        for (int i = 0; i < nb; ++i) { int v = bsum[i]; bsum[i] = acc; acc += v; }
    }
}

__global__ __launch_bounds__(256) void scan3(const int* __restrict__ counts, const int* __restrict__ bsum,
                                             int* __restrict__ row_ptr, int* __restrict__ cursor) {
    __shared__ int sd[256];
    int i = blockIdx.x * 256 + threadIdx.x;
    int v = (i < NN) ? counts[i] : 0;
    sd[threadIdx.x] = v;
    __syncthreads();
    for (int s = 1; s < 256; s <<= 1) {
        int t = sd[threadIdx.x];
        int u = (threadIdx.x >= s) ? sd[threadIdx.x - s] : 0;
        __syncthreads();
        sd[threadIdx.x] = t + u;
        __syncthreads();
    }
    int excl = sd[threadIdx.x] - v + bsum[blockIdx.x];
    if (i < NN) { row_ptr[i] = excl; cursor[i] = excl; }
    if (i == 0) row_ptr[NN] = ET;
}

__global__ void fill_csr(const int* __restrict__ ei, int* __restrict__ cursor, int* __restrict__ col) {
    int e = blockIdx.x * blockDim.x + threadIdx.x;
    if (e >= ET) return;
    int s, d;
    if (e < NE) { s = ei[e]; d = ei[NE + e]; } else { s = d = e - NE; }
    int pos = atomicAdd(&cursor[d], 1);
    col[pos] = s;
}

// ---------- per-dst-node online-softmax aggregation ----------
__global__ __launch_bounds__(64) void aggregate(const bf16* __restrict__ H,
                                                const float* __restrict__ a_src,
                                                const float* __restrict__ a_dst,
                                                const int* __restrict__ row_ptr,
                                                const int* __restrict__ col,
                                                const float* __restrict__ bias,
                                                float* __restrict__ out) {
    const int n = blockIdx.x;
    const int l = threadIdx.x;          // owns columns 2l, 2l+1
    float ad4[NH];
    #pragma unroll
    for (int h = 0; h < NH; ++h) ad4[h] = a_dst[n * NH + h];
    float m[NH], s[NH];
    float2 acc[NH];
    #pragma unroll
    for (int h = 0; h < NH; ++h) { m[h] = -INFINITY; s[h] = 0.f; acc[h] = make_float2(0.f, 0.f); }
    const int start = row_ptr[n], end = row_ptr[n + 1];
    const bf162* __restrict__ H2 = reinterpret_cast<const bf162*>(H);
    for (int j = start; j < end; ++j) {
        int sidx = col[j];
        float4 asr = *reinterpret_cast<const float4*>(&a_src[sidx * 4]);
        float lg[NH] = {asr.x + ad4[0], asr.y + ad4[1], asr.z + ad4[2], asr.w + ad4[3]};
        #pragma unroll
        for (int h = 0; h < NH; ++h) {
            lg[h] = lg[h] > 0.f ? lg[h] : 0.2f * lg[h];   // leaky_relu 0.2
            float nm = fmaxf(m[h], lg[h]);
            float sc = __expf(m[h] - nm);
            float p  = __expf(lg[h] - nm);
            bf162 hv = H2[sidx * 256 + h * 64 + l];
            acc[h].x = acc[h].x * sc + p * __bfloat162float(hv.x);
            acc[h].y = acc[h].y * sc + p * __bfloat162float(hv.y);
            s[h] = s[h] * sc + p;
            m[h] = nm;
        }
    }
    float o0 = 0.f, o1 = 0.f;
    #pragma unroll
    for (int h = 0; h < NH; ++h) { o0 += acc[h].x / s[h]; o1 += acc[h].y / s[h]; }
    int c0 = 2 * l;
    out[n * DF + c0]     = 0.25f * o0 + bias[c0];
    out[n * DF + c0 + 1] = 0.25f * o1 + bias[c0 + 1];
}

// ---------- BatchNorm stats (column-wise over N) ----------
__global__ __launch_bounds__(256) void bn_stats(const float* __restrict__ x, float* __restrict__ stats) {
    const int c = threadIdx.x & 127;
    const int half = threadIdx.x >> 7;
    float sum = 0.f, sq = 0.f;
    for (int r = blockIdx.x * 2 + half; r < NN; r += gridDim.x * 2) {
        float v = x[r * DF + c];
        sum += v; sq += v * v;
    }
    __shared__ float s1[256], s2[256];
    s1[threadIdx.x] = sum; s2[threadIdx.x] = sq;
    __syncthreads();
    if (threadIdx.x < 128) {
        atomicAdd(&stats[c], s1[threadIdx.x] + s1[threadIdx.x + 128]);
        atomicAdd(&stats[128 + c], s2[threadIdx.x] + s2[threadIdx.x + 128]);
    }
}

__global__ __launch_bounds__(256) void bn_apply(const float* __restrict__ x, const float* __restrict__ stats,
                                                const float* __restrict__ gamma, const float* __restrict__ beta,
                                                float* __restrict__ out) {
    int i = blockIdx.x * blockDim.x + threadIdx.x;
    if (i >= NN * DF) return;
    int c = i & 127;
    float mu = stats[c] * (1.f / NN);
    float var = stats[128 + c] * (1.f / NN) - mu * mu;
    float v = (x[i] - mu) * rsqrtf(var + BN_EPS) * gamma[c] + beta[c];
    out[i] = fmaxf(v, 0.f);
}

extern "C" void kernel_launch(void* const* d_in, const int* in_sizes, int n_in,
                              void* d_out, int out_size, void* d_ws, size_t ws_size,
                              hipStream_t stream) {
    (void)in_sizes; (void)n_in; (void)out_size; (void)ws_size;
    const float* x   = (const float*)d_in[0];
    const int*   ei  = (const int*)d_in[1];
    const float* W1  = (const float*)d_in[2];
    const float* as1 = (const float*)d_in[3];
    const float* ad1 = (const float*)d_in[4];
    const float* b1  = (const float*)d_in[5];
    const float* g1  = (const float*)d_in[6];
    const float* be1 = (const float*)d_in[7];
    const float* W2  = (const float*)d_in[8];
    const float* as2 = (const float*)d_in[9];
    const float* ad2 = (const float*)d_in[10];
    const float* b2  = (const float*)d_in[11];
    const float* g2  = (const float*)d_in[12];
    const float* be2 = (const float*)d_in[13];
    float* out = (float*)d_out;

    char* ws = (char*)d_ws;
    size_t off = 0;
    auto alloc = [&](size_t bytes) -> void* {
        void* p = ws + off;
        off += (bytes + 255) & ~(size_t)255;
        return p;
    };
    bf16*  h       = (bf16*)alloc((size_t)NN * HD * 2);      // 51.2 MB
    float* a_src   = (float*)alloc((size_t)NN * NH * 4);
    float* a_dst   = (float*)alloc((size_t)NN * NH * 4);
    int*   row_ptr = (int*)alloc((size_t)(NN + 1) * 4);
    int*   cursor  = (int*)alloc((size_t)NN * 4);
    int*   counts  = (int*)alloc((size_t)NN * 4);
    int*   bsum    = (int*)alloc(256 * 4);
    int*   colidx  = (int*)alloc((size_t)ET * 4);
    float* xbuf    = (float*)alloc((size_t)NN * DF * 4);     // 25.6 MB
    float* agg     = (float*)alloc((size_t)NN * DF * 4);     // 25.6 MB
    float* stats   = (float*)alloc(256 * 4);

    const int NB = (NN + 255) / 256;        // 196
    const int EB = (ET + 255) / 256;        // 3321
    dim3 ggrid((NN + 63) / 64, HD / 32);    // 782 x 16

    // ---- CSR build (shared by both layers) ----
    hipMemsetAsync(counts, 0, (size_t)NN * 4, stream);
    count_deg<<<EB, 256, 0, stream>>>(ei, counts);
    scan1<<<NB, 256, 0, stream>>>(counts, bsum);
    scan2<<<1, 64, 0, stream>>>(bsum, NB);
    scan3<<<NB, 256, 0, stream>>>(counts, bsum, row_ptr, cursor);
    fill_csr<<<EB, 256, 0, stream>>>(ei, cursor, colidx);

    // ---- layer 1 ----
    gemm_proj<<<ggrid, 256, 0, stream>>>(x, W1, h, NN);
    att_scores<<<NN, 64, 0, stream>>>(h, as1, ad1, a_src, a_dst);
    aggregate<<<NN, 64, 0, stream>>>(h, a_src, a_dst, row_ptr, colidx, b1, agg);
    hipMemsetAsync(stats, 0, 256 * 4, stream);
    bn_stats<<<200, 256, 0, stream>>>(agg, stats);
    bn_apply<<<(NN * DF + 255) / 256, 256, 0, stream>>>(agg, stats, g1, be1, xbuf);

    // ---- layer 2 ----
    gemm_proj<<<ggrid, 256, 0, stream>>>(xbuf, W2, h, NN);
    att_scores<<<NN, 64, 0, stream>>>(h, as2, ad2, a_src, a_dst);
    aggregate<<<NN, 64, 0, stream>>>(h, a_src, a_dst, row_ptr, colidx, b2, agg);
    hipMemsetAsync(stats, 0, 256 * 4, stream);
    bn_stats<<<200, 256, 0, stream>>>(agg, stats);
    bn_apply<<<(NN * DF + 255) / 256, 256, 0, stream>>>(agg, stats, g2, be2, out);
}

// Round 2
// 577.903 us; speedup vs baseline: 1.6815x; 1.6815x over previous
//
#include <hip/hip_runtime.h>
#include <hip/hip_bf16.h>
#include <math.h>

#define NN 50000
#define NP 50048            // NN padded to 64-row tiles
#define NE 800000
#define ET (NE + NN)
#define DF 128
#define NH 4
#define HD 512
#define BN_EPS 1e-5f

typedef __hip_bfloat16 bf16;
typedef __hip_bfloat162 bf162;
typedef __attribute__((ext_vector_type(8))) short bf16x8;
typedef __attribute__((ext_vector_type(4))) float f32x4;

// ---------- input conversions ----------
__global__ __launch_bounds__(256) void cvt_x_bf16(const float* __restrict__ in, bf16* __restrict__ out) {
    int i = blockIdx.x * 256 + threadIdx.x;            // 4 elements per thread
    if (i >= NN * DF / 4) return;
    float4 v = reinterpret_cast<const float4*>(in)[i];
    union { bf16 b[4]; short4 s; } u;
    u.b[0] = __float2bfloat16(v.x); u.b[1] = __float2bfloat16(v.y);
    u.b[2] = __float2bfloat16(v.z); u.b[3] = __float2bfloat16(v.w);
    reinterpret_cast<short4*>(out)[i] = u.s;
}

// W [128,512] f32 -> Wt [512,128] bf16
__global__ __launch_bounds__(256) void cvt_wt(const float* __restrict__ W, bf16* __restrict__ Wt) {
    int i = blockIdx.x * 256 + threadIdx.x;
    if (i >= HD * DF) return;
    int c = i >> 7, k = i & 127;
    Wt[i] = __float2bfloat16(W[k * HD + c]);
}

// ---------- MFMA GEMM: Hout[M,512](bf16) = A[M,128](bf16) @ Wt[512,128]^T ----------
__global__ __launch_bounds__(256) void gemm_mfma(const bf16* __restrict__ A,
                                                 const bf16* __restrict__ Bt,
                                                 bf16* __restrict__ Hout, int M) {
    __shared__ __align__(16) char As[16384];   // [64 rows][128 k] bf16, XOR-swizzled
    __shared__ __align__(16) char Bs[16384];   // [64 cols][128 k] bf16, XOR-swizzled
    const int tid = threadIdx.x;
    const int m0 = blockIdx.x * 64;
    const int n0 = blockIdx.y * 64;
    const char* Ab = (const char*)(A + (size_t)m0 * DF);
    const char* Bb = (const char*)(Bt + (size_t)n0 * DF);
    // linear LDS dest + inverse-swizzled global source (Guideline 21)
    #pragma unroll
    for (int i = 0; i < 4; ++i) {
        int d = (tid + i * 256) * 16;
        int s = d ^ (((d >> 8) & 7) << 4);
        __builtin_amdgcn_global_load_lds((const __attribute__((address_space(1))) void*)(Ab + s),
                                         (__attribute__((address_space(3))) void*)(As + d), 16, 0, 0);
    }
    #pragma unroll
    for (int i = 0; i < 4; ++i) {
        int d = (tid + i * 256) * 16;
        int s = d ^ (((d >> 8) & 7) << 4);
        __builtin_amdgcn_global_load_lds((const __attribute__((address_space(1))) void*)(Bb + s),
                                         (__attribute__((address_space(3))) void*)(Bs + d), 16, 0, 0);
    }
    __syncthreads();
    const int lane = tid & 63;
    const int wave = tid >> 6;
    const int wm = (wave & 1) * 32;
    const int wn = (wave >> 1) * 32;
    const int lr = lane & 15;
    const int lkb = (lane >> 4) * 16;          // k-byte offset within 64B k-group
    f32x4 acc[2][2] = {};
    #pragma unroll
    for (int kk = 0; kk < 4; ++kk) {
        int kb = kk * 64 + lkb;
        int ra0 = wm + lr, ra1 = wm + 16 + lr;
        int rb0 = wn + lr, rb1 = wn + 16 + lr;
        bf16x8 a0 = *(const bf16x8*)(As + ((ra0 * 256 + kb) ^ ((ra0 & 7) << 4)));
        bf16x8 a1 = *(const bf16x8*)(As + ((ra1 * 256 + kb) ^ ((ra1 & 7) << 4)));
        bf16x8 b0 = *(const bf16x8*)(Bs + ((rb0 * 256 + kb) ^ ((rb0 & 7) << 4)));
        bf16x8 b1 = *(const bf16x8*)(Bs + ((rb1 * 256 + kb) ^ ((rb1 & 7) << 4)));
        acc[0][0] = __builtin_amdgcn_mfma_f32_16x16x32_bf16(a0, b0, acc[0][0], 0, 0, 0);
        acc[0][1] = __builtin_amdgcn_mfma_f32_16x16x32_bf16(a0, b1, acc[0][1], 0, 0, 0);
        acc[1][0] = __builtin_amdgcn_mfma_f32_16x16x32_bf16(a1, b0, acc[1][0], 0, 0, 0);
        acc[1][1] = __builtin_amdgcn_mfma_f32_16x16x32_bf16(a1, b1, acc[1][1], 0, 0, 0);
    }
    const int orow = (lane >> 4) * 4;
    #pragma unroll
    for (int mi = 0; mi < 2; ++mi) {
        #pragma unroll
        for (int r = 0; r < 4; ++r) {
            int gr = m0 + wm + mi * 16 + orow + r;
            if (gr < M) {
                #pragma unroll
                for (int ni = 0; ni < 2; ++ni)
                    Hout[(size_t)gr * HD + n0 + wn + ni * 16 + lr] = __float2bfloat16(acc[mi][ni][r]);
            }
        }
    }
}

// ---------- per-node attention scores ----------
__global__ __launch_bounds__(64) void att_scores(const bf16* __restrict__ H,
                                                 const float* __restrict__ as,
                                                 const float* __restrict__ ad,
                                                 float* __restrict__ a_src,
                                                 float* __restrict__ a_dst) {
    const int n = blockIdx.x;
    const int l = threadIdx.x;
    float ps[NH], pd[NH];
    #pragma unroll
    for (int h = 0; h < NH; ++h) {
        float v0 = __bfloat162float(H[n * HD + h * DF + l]);
        float v1 = __bfloat162float(H[n * HD + h * DF + l + 64]);
        ps[h] = v0 * as[h * DF + l] + v1 * as[h * DF + l + 64];
        pd[h] = v0 * ad[h * DF + l] + v1 * ad[h * DF + l + 64];
    }
    #pragma unroll
    for (int off = 32; off > 0; off >>= 1) {
        #pragma unroll
        for (int h = 0; h < NH; ++h) {
            ps[h] += __shfl_down(ps[h], off);
            pd[h] += __shfl_down(pd[h], off);
        }
    }
    if (l == 0) {
        #pragma unroll
        for (int h = 0; h < NH; ++h) {
            a_src[n * NH + h] = ps[h];
            a_dst[n * NH + h] = pd[h];
        }
    }
}

// ---------- CSR build ----------
__global__ void count_deg(const int* __restrict__ ei, int* __restrict__ counts) {
    int e = blockIdx.x * blockDim.x + threadIdx.x;
    if (e >= ET) return;
    int d = (e < NE) ? ei[NE + e] : (e - NE);
    atomicAdd(&counts[d], 1);
}

__global__ __launch_bounds__(256) void scan1(const int* __restrict__ counts, int* __restrict__ bsum) {
    __shared__ int sd[256];
    int i = blockIdx.x * 256 + threadIdx.x;
    sd[threadIdx.x] = (i < NN) ? counts[i] : 0;
    __syncthreads();
    for (int s = 128; s > 0; s >>= 1) {
        if (threadIdx.x < s) sd[threadIdx.x] += sd[threadIdx.x + s];
        __syncthreads();
    }
    if (threadIdx.x == 0) bsum[blockIdx.x] = sd[0];
}

__global__ void scan2(int* __restrict__ bsum, int nb) {
    if (threadIdx.x == 0 && blockIdx.x == 0) {
        int acc = 0;
        for (int i = 0; i < nb; ++i) { int v = bsum[i]; bsum[i] = acc; acc += v; }
    }
}

__global__ __launch_bounds__(256) void scan3(const int* __restrict__ counts, const int* __restrict__ bsum,
                                             int* __restrict__ row_ptr, int* __restrict__ cursor) {
    __shared__ int sd[256];
    int i = blockIdx.x * 256 + threadIdx.x;
    int v = (i < NN) ? counts[i] : 0;
    sd[threadIdx.x] = v;
    __syncthreads();
    for (int s = 1; s < 256; s <<= 1) {
        int t = sd[threadIdx.x];
        int u = (threadIdx.x >= s) ? sd[threadIdx.x - s] : 0;
        __syncthreads();
        sd[threadIdx.x] = t + u;
        __syncthreads();
    }
    int excl = sd[threadIdx.x] - v + bsum[blockIdx.x];
    if (i < NN) { row_ptr[i] = excl; cursor[i] = excl; }
    if (i == 0) row_ptr[NN] = ET;
}

__global__ void fill_csr(const int* __restrict__ ei, int* __restrict__ cursor, int* __restrict__ col) {
    int e = blockIdx.x * blockDim.x + threadIdx.x;
    if (e >= ET) return;
    int s, d;
    if (e < NE) { s = ei[e]; d = ei[NE + e]; } else { s = d = e - NE; }
    int pos = atomicAdd(&cursor[d], 1);
    col[pos] = s;
}

// ---------- per-dst-node online-softmax aggregation ----------
__global__ __launch_bounds__(64) void aggregate(const bf16* __restrict__ H,
                                                const float* __restrict__ a_src,
                                                const float* __restrict__ a_dst,
                                                const int* __restrict__ row_ptr,
                                                const int* __restrict__ col,
                                                const float* __restrict__ bias,
                                                float* __restrict__ out) {
    const int n = blockIdx.x;
    const int l = threadIdx.x;          // owns columns 2l, 2l+1
    float ad4[NH];
    #pragma unroll
    for (int h = 0; h < NH; ++h) ad4[h] = a_dst[n * NH + h];
    float m[NH], s[NH];
    float2 acc[NH];
    #pragma unroll
    for (int h = 0; h < NH; ++h) { m[h] = -INFINITY; s[h] = 0.f; acc[h] = make_float2(0.f, 0.f); }
    const int start = row_ptr[n], end = row_ptr[n + 1];
    const bf162* __restrict__ H2 = reinterpret_cast<const bf162*>(H);
    for (int j = start; j < end; ++j) {
        int sidx = col[j];
        float4 asr = *reinterpret_cast<const float4*>(&a_src[sidx * 4]);
        float lg[NH] = {asr.x + ad4[0], asr.y + ad4[1], asr.z + ad4[2], asr.w + ad4[3]};
        #pragma unroll
        for (int h = 0; h < NH; ++h) {
            lg[h] = lg[h] > 0.f ? lg[h] : 0.2f * lg[h];   // leaky_relu 0.2
            float nm = fmaxf(m[h], lg[h]);
            float sc = __expf(m[h] - nm);
            float p  = __expf(lg[h] - nm);
            bf162 hv = H2[sidx * 256 + h * 64 + l];
            acc[h].x = acc[h].x * sc + p * __bfloat162float(hv.x);
            acc[h].y = acc[h].y * sc + p * __bfloat162float(hv.y);
            s[h] = s[h] * sc + p;
            m[h] = nm;
        }
    }
    float o0 = 0.f, o1 = 0.f;
    #pragma unroll
    for (int h = 0; h < NH; ++h) { o0 += acc[h].x / s[h]; o1 += acc[h].y / s[h]; }
    int c0 = 2 * l;
    out[n * DF + c0]     = 0.25f * o0 + bias[c0];
    out[n * DF + c0 + 1] = 0.25f * o1 + bias[c0 + 1];
}

// ---------- BatchNorm ----------
__global__ __launch_bounds__(256) void bn_stats(const float* __restrict__ x, float* __restrict__ stats) {
    const int c = threadIdx.x & 127;
    const int half = threadIdx.x >> 7;
    float sum = 0.f, sq = 0.f;
    for (int r = blockIdx.x * 2 + half; r < NN; r += gridDim.x * 2) {
        float v = x[r * DF + c];
        sum += v; sq += v * v;
    }
    __shared__ float s1[256], s2[256];
    s1[threadIdx.x] = sum; s2[threadIdx.x] = sq;
    __syncthreads();
    if (threadIdx.x < 128) {
        atomicAdd(&stats[c], s1[threadIdx.x] + s1[threadIdx.x + 128]);
        atomicAdd(&stats[128 + c], s2[threadIdx.x] + s2[threadIdx.x + 128]);
    }
}

// layer-1 variant: emit bf16 (feeds layer-2 MFMA GEMM)
__global__ __launch_bounds__(256) void bn_apply_bf16(const float* __restrict__ x, const float* __restrict__ stats,
                                                     const float* __restrict__ gamma, const float* __restrict__ beta,
                                                     bf16* __restrict__ out) {
    int i = blockIdx.x * blockDim.x + threadIdx.x;
    if (i >= NN * DF) return;
    int c = i & 127;
    float mu = stats[c] * (1.f / NN);
    float var = stats[128 + c] * (1.f / NN) - mu * mu;
    float v = (x[i] - mu) * rsqrtf(var + BN_EPS) * gamma[c] + beta[c];
    out[i] = __float2bfloat16(fmaxf(v, 0.f));
}

__global__ __launch_bounds__(256) void bn_apply(const float* __restrict__ x, const float* __restrict__ stats,
                                                const float* __restrict__ gamma, const float* __restrict__ beta,
                                                float* __restrict__ out) {
    int i = blockIdx.x * blockDim.x + threadIdx.x;
    if (i >= NN * DF) return;
    int c = i & 127;
    float mu = stats[c] * (1.f / NN);
    float var = stats[128 + c] * (1.f / NN) - mu * mu;
    float v = (x[i] - mu) * rsqrtf(var + BN_EPS) * gamma[c] + beta[c];
    out[i] = fmaxf(v, 0.f);
}

extern "C" void kernel_launch(void* const* d_in, const int* in_sizes, int n_in,
                              void* d_out, int out_size, void* d_ws, size_t ws_size,
                              hipStream_t stream) {
    (void)in_sizes; (void)n_in; (void)out_size; (void)ws_size;
    const float* x   = (const float*)d_in[0];
    const int*   ei  = (const int*)d_in[1];
    const float* W1  = (const float*)d_in[2];
    const float* as1 = (const float*)d_in[3];
    const float* ad1 = (const float*)d_in[4];
    const float* b1  = (const float*)d_in[5];
    const float* g1  = (const float*)d_in[6];
    const float* be1 = (const float*)d_in[7];
    const float* W2  = (const float*)d_in[8];
    const float* as2 = (const float*)d_in[9];
    const float* ad2 = (const float*)d_in[10];
    const float* b2  = (const float*)d_in[11];
    const float* g2  = (const float*)d_in[12];
    const float* be2 = (const float*)d_in[13];
    float* out = (float*)d_out;

    char* ws = (char*)d_ws;
    size_t off = 0;
    auto alloc = [&](size_t bytes) -> void* {
        void* p = ws + off;
        off += (bytes + 255) & ~(size_t)255;
        return p;
    };
    bf16*  h       = (bf16*)alloc((size_t)NN * HD * 2);      // 51.2 MB
    bf16*  xb      = (bf16*)alloc((size_t)NP * DF * 2);      // 12.8 MB (padded)
    bf16*  Wt1     = (bf16*)alloc((size_t)HD * DF * 2);
    bf16*  Wt2     = (bf16*)alloc((size_t)HD * DF * 2);
    float* a_src   = (float*)alloc((size_t)NN * NH * 4);
    float* a_dst   = (float*)alloc((size_t)NN * NH * 4);
    int*   row_ptr = (int*)alloc((size_t)(NN + 1) * 4);
    int*   cursor  = (int*)alloc((size_t)NN * 4);
    int*   counts  = (int*)alloc((size_t)NN * 4);
    int*   bsum    = (int*)alloc(256 * 4);
    int*   colidx  = (int*)alloc((size_t)ET * 4);
    float* agg     = (float*)alloc((size_t)NN * DF * 4);     // 25.6 MB
    float* stats   = (float*)alloc(256 * 4);

    const int NB = (NN + 255) / 256;        // 196
    const int EB = (ET + 255) / 256;        // 3321
    dim3 ggrid(NP / 64, HD / 64);           // 782 x 8

    // ---- dtype prep + CSR build ----
    cvt_x_bf16<<<(NN * DF / 4 + 255) / 256, 256, 0, stream>>>(x, xb);
    cvt_wt<<<(HD * DF + 255) / 256, 256, 0, stream>>>(W1, Wt1);
    cvt_wt<<<(HD * DF + 255) / 256, 256, 0, stream>>>(W2, Wt2);
    hipMemsetAsync(counts, 0, (size_t)NN * 4, stream);
    count_deg<<<EB, 256, 0, stream>>>(ei, counts);
    scan1<<<NB, 256, 0, stream>>>(counts, bsum);
    scan2<<<1, 64, 0, stream>>>(bsum, NB);
    scan3<<<NB, 256, 0, stream>>>(counts, bsum, row_ptr, cursor);
    fill_csr<<<EB, 256, 0, stream>>>(ei, cursor, colidx);

    // ---- layer 1 ----
    gemm_mfma<<<ggrid, 256, 0, stream>>>(xb, Wt1, h, NN);
    att_scores<<<NN, 64, 0, stream>>>(h, as1, ad1, a_src, a_dst);
    aggregate<<<NN, 64, 0, stream>>>(h, a_src, a_dst, row_ptr, colidx, b1, agg);
    hipMemsetAsync(stats, 0, 256 * 4, stream);
    bn_stats<<<200, 256, 0, stream>>>(agg, stats);
    bn_apply_bf16<<<(NN * DF + 255) / 256, 256, 0, stream>>>(agg, stats, g1, be1, xb);

    // ---- layer 2 ----
    gemm_mfma<<<ggrid, 256, 0, stream>>>(xb, Wt2, h, NN);
    att_scores<<<NN, 64, 0, stream>>>(h, as2, ad2, a_src, a_dst);
    aggregate<<<NN, 64, 0, stream>>>(h, a_src, a_dst, row_ptr, colidx, b2, agg);
    hipMemsetAsync(stats, 0, 256 * 4, stream);
    bn_stats<<<200, 256, 0, stream>>>(agg, stats);
    bn_apply<<<(NN * DF + 255) / 256, 256, 0, stream>>>(agg, stats, g2, be2, out);
}